// Round 6
// baseline (220.874 us; speedup 1.0000x reference)
//
#include <hip/hip_runtime.h>
#include <math.h>

// Problem constants
#define B_SZ   512
#define L_SEQ  30
#define F_DIM  64
#define N_LEAD 500
#define MAXLAG 10
#define H_DIM  64
#define NROWS  5000          // N_LEAD * MAXLAG
#define TOPK   5

// Output layout (flat float32):
// pred [512] | top_k_indices [512*5*2] | top_k_scores [512*5] | attn [512*5000]
#define OFF_IDX   512
#define OFF_SCORE 5632
#define OFF_ATTN  8192

typedef float v4f __attribute__((ext_vector_type(4)));

__device__ __forceinline__ float fast_sigmoid(float x) {
    return 1.f / (1.f + __expf(-x));
}
__device__ __forceinline__ float fast_tanh(float x) {
    float ax = fabsf(x);
    float t  = __expf(-2.f * ax);
    float r  = (1.f - t) / (1.f + t);
    return copysignf(r, x);
}

// 16 x float4 dot with 4 partial accumulators
__device__ __forceinline__ float dot16(const float4* __restrict__ w,
                                       const float4* __restrict__ v) {
    float a0 = 0.f, a1 = 0.f, a2 = 0.f, a3 = 0.f;
#pragma unroll
    for (int k = 0; k < 16; k += 4) {
        a0 += w[k+0].x*v[k+0].x + w[k+0].y*v[k+0].y + w[k+0].z*v[k+0].z + w[k+0].w*v[k+0].w;
        a1 += w[k+1].x*v[k+1].x + w[k+1].y*v[k+1].y + w[k+1].z*v[k+1].z + w[k+1].w*v[k+1].w;
        a2 += w[k+2].x*v[k+2].x + w[k+2].y*v[k+2].y + w[k+2].z*v[k+2].z + w[k+2].w*v[k+2].w;
        a3 += w[k+3].x*v[k+3].x + w[k+3].y*v[k+3].y + w[k+3].z*v[k+3].z + w[k+3].w*v[k+3].w;
    }
    return (a0 + a1) + (a2 + a3);
}

// ---------------------------------------------------------------------------
// Kernel A: LSTM (30 steps) + query = h@W_Q^T + kq = query@W_K  -> kq[B,64]
// Kept separate so its 128-VGPR weight cache can't throttle streaming occupancy.
// ---------------------------------------------------------------------------
__global__ __launch_bounds__(256) void lstm_kq_kernel(
    const float* __restrict__ x,      // [B,30,64]
    const float* __restrict__ W_ih,   // [256,64]
    const float* __restrict__ W_hh,   // [256,64]
    const float* __restrict__ b_ih,   // [256]
    const float* __restrict__ b_hh,   // [256]
    const float* __restrict__ W_Q,    // [64,64]
    const float* __restrict__ W_K,    // [64,64]
    float* __restrict__ kq)           // [B,64]
{
    __shared__ __align__(16) float xs[L_SEQ * F_DIM];   // 7.5 KB
    __shared__ __align__(16) float hs[H_DIM];
    __shared__ __align__(16) float gates[256];

    const int b = blockIdx.x;
    const int t = threadIdx.x;

    for (int i = t; i < L_SEQ * F_DIM; i += 256)
        xs[i] = x[b * L_SEQ * F_DIM + i];
    if (t < H_DIM) hs[t] = 0.f;

    float4 wih[16], whh[16];
    const float4* wihp = (const float4*)(W_ih + t * 64);
    const float4* whhp = (const float4*)(W_hh + t * 64);
#pragma unroll
    for (int k = 0; k < 16; ++k) { wih[k] = wihp[k]; whh[k] = whhp[k]; }
    const float bsum = b_ih[t] + b_hh[t];

    float c = 0.f;
    __syncthreads();

    float gx = bsum + dot16(wih, (const float4*)xs);

    for (int step = 0; step < L_SEQ; ++step) {
        float g = gx + dot16(whh, (const float4*)hs);
        gates[t] = g;
        __syncthreads();
        if (t < H_DIM) {
            float ig = fast_sigmoid(gates[t]);
            float fg = fast_sigmoid(gates[t + 64]);
            float gg = fast_tanh(gates[t + 128]);
            float og = fast_sigmoid(gates[t + 192]);
            c = fg * c + ig * gg;
            hs[t] = og * fast_tanh(c);
        }
        if (step + 1 < L_SEQ)
            gx = bsum + dot16(wih, (const float4*)(xs + (step + 1) * F_DIM));
        __syncthreads();
    }

    if (t < H_DIM)
        gates[t] = dot16((const float4*)(W_Q + t * 64), (const float4*)hs);
    __syncthreads();
    if (t < F_DIM) {
        float a0 = 0.f, a1 = 0.f;
        for (int h = 0; h < H_DIM; h += 2) {
            a0 += gates[h]     * W_K[h * F_DIM + t];
            a1 += gates[h + 1] * W_K[(h + 1) * F_DIM + t];
        }
        kq[b * F_DIM + t] = a0 + a1;
    }
}

// ---------------------------------------------------------------------------
// Kernel B (fused): NT streaming GEMV (16-lane-coop, wave-contiguous — proven
// best) -> av in LDS + NT store to attn out -> top-5 -> softmax -> gather -> MLP.
// One block per batch, 512 threads.
// ---------------------------------------------------------------------------
__global__ __launch_bounds__(512) void fused_attn_topk_kernel(
    const float* __restrict__ raw,    // [B*5000*64]
    const float* __restrict__ kq,     // [B,64]
    const float* __restrict__ Wp1, const float* __restrict__ bp1,
    const float* __restrict__ Wp2, const float* __restrict__ bp2,
    const float* __restrict__ Wp3, const float* __restrict__ bp3,
    float* __restrict__ out)
{
    __shared__ __align__(16) float av[NROWS];       // 20 KB
    __shared__ float redv[8];
    __shared__ int   redi[8];
    __shared__ float topv[TOPK];
    __shared__ int   topi[TOPK];
    __shared__ float sc[TOPK];
    __shared__ __align__(16) float wsum[64];
    __shared__ __align__(16) float h1[64];
    __shared__ float h2[32];

    const int b   = blockIdx.x, t = threadIdx.x;
    const int sub = t & 15;          // 0..15: float4 position within row
    const int rg  = t >> 4;          // 0..31: row group

    // per-lane kq fragment (one-time global read, broadcast across waves)
    const float4 kqv = ((const float4*)(kq + b * 64))[sub];

    const float* rawb = raw + ((size_t)b * NROWS) * 64;
    float* attn_g = out + OFF_ATTN + (size_t)b * NROWS;

#define ROWDOT(row) { \
    const v4f* pp = (const v4f*)(rawb + (size_t)(row) * 64) + sub; \
    v4f v = __builtin_nontemporal_load(pp); \
    float s = v.x * kqv.x + v.y * kqv.y + v.z * kqv.z + v.w * kqv.w; \
    s += __shfl_xor(s, 8); \
    s += __shfl_xor(s, 4); \
    s += __shfl_xor(s, 2); \
    s += __shfl_xor(s, 1); \
    if (sub == 0) { \
        float sv = s * 0.125f; \
        av[row] = sv; \
        __builtin_nontemporal_store(sv, attn_g + (row)); \
    } }

    // 39 iterations x 128 rows (4 independent 32-row groups) = 4992 rows
#pragma unroll 1
    for (int i4 = 0; i4 < 39; ++i4) {
        int r0 = i4 * 128 + rg;
        ROWDOT(r0)
        ROWDOT(r0 + 32)
        ROWDOT(r0 + 64)
        ROWDOT(r0 + 96)
    }
    if (rg < 8) { ROWDOT(4992 + rg) }   // tail rows 4992..4999
#undef ROWDOT
    __syncthreads();

    // ---- top-5, lax.top_k tie semantics (ties -> lowest index) ----
    for (int pp = 0; pp < TOPK; ++pp) {
        float bv = -INFINITY; int bi = 0x7fffffff;
        for (int i = t; i < NROWS; i += 512) {
            float v = av[i];
            if (v > bv || (v == bv && i < bi)) { bv = v; bi = i; }
        }
#pragma unroll
        for (int m = 32; m >= 1; m >>= 1) {
            float ov = __shfl_xor(bv, m);
            int   oi = __shfl_xor(bi, m);
            if (ov > bv || (ov == bv && oi < bi)) { bv = ov; bi = oi; }
        }
        if ((t & 63) == 0) { redv[t >> 6] = bv; redi[t >> 6] = bi; }
        __syncthreads();
        if (t == 0) {
            for (int w = 1; w < 8; ++w)
                if (redv[w] > bv || (redv[w] == bv && redi[w] < bi)) { bv = redv[w]; bi = redi[w]; }
            topv[pp] = bv; topi[pp] = bi;
            av[bi] = -INFINITY;
        }
        __syncthreads();
    }

    // ---- softmax + index outputs ----
    if (t == 0) {
        float mx = topv[0];
        float e[TOPK], s = 0.f;
#pragma unroll
        for (int k = 0; k < TOPK; ++k) { e[k] = __expf(topv[k] - mx); s += e[k]; }
        float inv = 1.f / s;
#pragma unroll
        for (int k = 0; k < TOPK; ++k) {
            sc[k] = e[k] * inv;
            out[OFF_IDX + b * 10 + 2 * k]     = (float)(topi[k] / MAXLAG);
            out[OFF_IDX + b * 10 + 2 * k + 1] = (float)(topi[k] % MAXLAG);
            out[OFF_SCORE + b * TOPK + k]     = sc[k];
        }
    }
    __syncthreads();

    // ---- gather + MLP ----
    if (t < 64) {
        float acc = 0.f;
#pragma unroll
        for (int k = 0; k < TOPK; ++k)
            acc += sc[k] * rawb[(size_t)topi[k] * 64 + t];
        wsum[t] = acc;
    }
    __syncthreads();
    if (t < 64) {
        float a = bp1[t];
        const float4* w = (const float4*)(Wp1 + t * 64);
        const float4* v = (const float4*)wsum;
#pragma unroll
        for (int k = 0; k < 16; ++k)
            a += w[k].x*v[k].x + w[k].y*v[k].y + w[k].z*v[k].z + w[k].w*v[k].w;
        h1[t] = fmaxf(a, 0.f);
    }
    __syncthreads();
    if (t < 32) {
        float a = bp2[t];
        const float4* w = (const float4*)(Wp2 + t * 64);
        const float4* v = (const float4*)h1;
#pragma unroll
        for (int k = 0; k < 16; ++k)
            a += w[k].x*v[k].x + w[k].y*v[k].y + w[k].z*v[k].z + w[k].w*v[k].w;
        h2[t] = fmaxf(a, 0.f);
    }
    __syncthreads();
    if (t == 0) {
        float a = bp3[0];
#pragma unroll
        for (int f = 0; f < 32; ++f) a += Wp3[f] * h2[f];
        out[b] = a;
    }
}

// ---------------------------------------------------------------------------
extern "C" void kernel_launch(void* const* d_in, const int* in_sizes, int n_in,
                              void* d_out, int out_size, void* d_ws, size_t ws_size,
                              hipStream_t stream) {
    const float* target = (const float*)d_in[0];
    const float* raw    = (const float*)d_in[1];
    const float* W_ih   = (const float*)d_in[2];
    const float* W_hh   = (const float*)d_in[3];
    const float* b_ih   = (const float*)d_in[4];
    const float* b_hh   = (const float*)d_in[5];
    const float* W_Q    = (const float*)d_in[6];
    const float* W_K    = (const float*)d_in[7];
    const float* Wp1    = (const float*)d_in[8];
    const float* bp1    = (const float*)d_in[9];
    const float* Wp2    = (const float*)d_in[10];
    const float* bp2    = (const float*)d_in[11];
    const float* Wp3    = (const float*)d_in[12];
    const float* bp3    = (const float*)d_in[13];

    float* out = (float*)d_out;
    float* kq  = (float*)d_ws;                 // [512*64] floats

    hipLaunchKernelGGL(lstm_kq_kernel, dim3(B_SZ), dim3(256), 0, stream,
                       target, W_ih, W_hh, b_ih, b_hh, W_Q, W_K, kq);
    hipLaunchKernelGGL(fused_attn_topk_kernel, dim3(B_SZ), dim3(512), 0, stream,
                       raw, kq, Wp1, bp1, Wp2, bp2, Wp3, bp3, out);
}

// Round 7
// 193.245 us; speedup vs baseline: 1.1430x; 1.1430x over previous
//
#include <hip/hip_runtime.h>
#include <math.h>

// Problem constants
#define B_SZ   512
#define L_SEQ  30
#define F_DIM  64
#define N_LEAD 500
#define MAXLAG 10
#define H_DIM  64
#define NROWS  5000          // N_LEAD * MAXLAG
#define TOPK   5
#define CHUNKS 10
#define RPB    500           // rows per attn block

// Output layout (flat float32):
// pred [512] | top_k_indices [512*5*2] | top_k_scores [512*5] | attn [512*5000]
#define OFF_IDX   512
#define OFF_SCORE 5632
#define OFF_ATTN  8192

// Workspace layout (floats):
// kq [512*64] | pval [512*10*5] | pidx [512*10*5] (as int)
#define WS_PVAL 32768
#define WS_PIDX 58368

typedef float v4f __attribute__((ext_vector_type(4)));

__device__ __forceinline__ float fast_sigmoid(float x) {
    return 1.f / (1.f + __expf(-x));
}
__device__ __forceinline__ float fast_tanh(float x) {
    float ax = fabsf(x);
    float t  = __expf(-2.f * ax);
    float r  = (1.f - t) / (1.f + t);
    return copysignf(r, x);
}

__device__ __forceinline__ float dot16(const float4* __restrict__ w,
                                       const float4* __restrict__ v) {
    float a0 = 0.f, a1 = 0.f, a2 = 0.f, a3 = 0.f;
#pragma unroll
    for (int k = 0; k < 16; k += 4) {
        a0 += w[k+0].x*v[k+0].x + w[k+0].y*v[k+0].y + w[k+0].z*v[k+0].z + w[k+0].w*v[k+0].w;
        a1 += w[k+1].x*v[k+1].x + w[k+1].y*v[k+1].y + w[k+1].z*v[k+1].z + w[k+1].w*v[k+1].w;
        a2 += w[k+2].x*v[k+2].x + w[k+2].y*v[k+2].y + w[k+2].z*v[k+2].z + w[k+2].w*v[k+2].w;
        a3 += w[k+3].x*v[k+3].x + w[k+3].y*v[k+3].y + w[k+3].z*v[k+3].z + w[k+3].w*v[k+3].w;
    }
    return (a0 + a1) + (a2 + a3);
}

// ---------------------------------------------------------------------------
// Kernel A: LSTM (30 steps) + query = h@W_Q^T + kq = query@W_K  -> kq[B,64]
// (unchanged; measured LSTM + total launch overhead ~ 20.5us)
// ---------------------------------------------------------------------------
__global__ __launch_bounds__(256) void lstm_kq_kernel(
    const float* __restrict__ x,
    const float* __restrict__ W_ih, const float* __restrict__ W_hh,
    const float* __restrict__ b_ih, const float* __restrict__ b_hh,
    const float* __restrict__ W_Q,  const float* __restrict__ W_K,
    float* __restrict__ kq)
{
    __shared__ __align__(16) float xs[L_SEQ * F_DIM];
    __shared__ __align__(16) float hs[H_DIM];
    __shared__ __align__(16) float gates[256];

    const int b = blockIdx.x;
    const int t = threadIdx.x;

    for (int i = t; i < L_SEQ * F_DIM; i += 256)
        xs[i] = x[b * L_SEQ * F_DIM + i];
    if (t < H_DIM) hs[t] = 0.f;

    float4 wih[16], whh[16];
    const float4* wihp = (const float4*)(W_ih + t * 64);
    const float4* whhp = (const float4*)(W_hh + t * 64);
#pragma unroll
    for (int k = 0; k < 16; ++k) { wih[k] = wihp[k]; whh[k] = whhp[k]; }
    const float bsum = b_ih[t] + b_hh[t];

    float c = 0.f;
    __syncthreads();

    float gx = bsum + dot16(wih, (const float4*)xs);

    for (int step = 0; step < L_SEQ; ++step) {
        float g = gx + dot16(whh, (const float4*)hs);
        gates[t] = g;
        __syncthreads();
        if (t < H_DIM) {
            float ig = fast_sigmoid(gates[t]);
            float fg = fast_sigmoid(gates[t + 64]);
            float gg = fast_tanh(gates[t + 128]);
            float og = fast_sigmoid(gates[t + 192]);
            c = fg * c + ig * gg;
            hs[t] = og * fast_tanh(c);
        }
        if (step + 1 < L_SEQ)
            gx = bsum + dot16(wih, (const float4*)(xs + (step + 1) * F_DIM));
        __syncthreads();
    }

    if (t < H_DIM)
        gates[t] = dot16((const float4*)(W_Q + t * 64), (const float4*)hs);
    __syncthreads();
    if (t < F_DIM) {
        float a0 = 0.f, a1 = 0.f;
        for (int h = 0; h < H_DIM; h += 2) {
            a0 += gates[h]     * W_K[h * F_DIM + t];
            a1 += gates[h + 1] * W_K[(h + 1) * F_DIM + t];
        }
        kq[b * F_DIM + t] = a0 + a1;
    }
}

// ---------------------------------------------------------------------------
// Kernel B: NT streaming GEMV (R5 structure: 5120 blocks x 256 thr, 16-lane
// coop, wave-contiguous) + 8-deep load pipeline + local top-5 of the block's
// 500 rows (chunk-decomposable under (val desc, idx asc) -> exact lax.top_k).
// ---------------------------------------------------------------------------
__global__ __launch_bounds__(256) void attn_stream_topk_kernel(
    const float* __restrict__ raw,    // [B*5000*64]
    const float* __restrict__ kq,     // [B,64]
    float* __restrict__ attn,         // [B*5000]  (output, NT store)
    float* __restrict__ pval,         // [B*10*5]
    int*   __restrict__ pidx)         // [B*10*5]
{
    __shared__ __align__(16) float av[512];
    __shared__ float redv[4];
    __shared__ int   redi[4];

    const int b     = blockIdx.x / CHUNKS;
    const int chunk = blockIdx.x % CHUNKS;
    const int t     = threadIdx.x;
    const int sub   = t & 15;    // float4 slot within row
    const int rg    = t >> 4;    // 0..15 row-group

    const float4 kqv = ((const float4*)(kq + b * 64))[sub];
    const int base = chunk * RPB;
    const float* rawb  = raw  + (size_t)b * NROWS * 64;
    float*       attng = attn + (size_t)b * NROWS + base;

    if (t < 12) av[500 + t] = -INFINITY;   // pad rows 500..511

#define ISSUE(vk, off) v4f vk = __builtin_nontemporal_load( \
        (const v4f*)(rawb + (size_t)(base + (off) + rg) * 64) + sub);
#define REDUCE(vk, off) { \
    float s = vk.x*kqv.x + vk.y*kqv.y + vk.z*kqv.z + vk.w*kqv.w; \
    s += __shfl_xor(s, 8); s += __shfl_xor(s, 4); \
    s += __shfl_xor(s, 2); s += __shfl_xor(s, 1); \
    if (sub == 0) { float sv = s * 0.125f; int lr = (off) + rg; \
        av[lr] = sv; __builtin_nontemporal_store(sv, attng + lr); } }

    // rows 0..383: three 128-row groups, 8 loads in flight each
#pragma unroll 1
    for (int p = 0; p < 384; p += 128) {
        ISSUE(v0, p +  0) ISSUE(v1, p + 16) ISSUE(v2, p + 32) ISSUE(v3, p + 48)
        ISSUE(v4, p + 64) ISSUE(v5, p + 80) ISSUE(v6, p + 96) ISSUE(v7, p +112)
        REDUCE(v0, p +  0) REDUCE(v1, p + 16) REDUCE(v2, p + 32) REDUCE(v3, p + 48)
        REDUCE(v4, p + 64) REDUCE(v5, p + 80) REDUCE(v6, p + 96) REDUCE(v7, p +112)
    }
    // rows 384..447
    {
        ISSUE(v0, 384) ISSUE(v1, 400) ISSUE(v2, 416) ISSUE(v3, 432)
        REDUCE(v0, 384) REDUCE(v1, 400) REDUCE(v2, 416) REDUCE(v3, 432)
    }
    // rows 448..499 (tail: 3 full 16-row groups + 4-row guarded group)
    {
        ISSUE(v0, 448) ISSUE(v1, 464) ISSUE(v2, 480)
        int lr = 496 + rg;
        int safe = lr < RPB ? lr : RPB - 1;
        v4f v3 = __builtin_nontemporal_load(
            (const v4f*)(rawb + (size_t)(base + safe) * 64) + sub);
        REDUCE(v0, 448) REDUCE(v1, 464) REDUCE(v2, 480)
        float s = v3.x*kqv.x + v3.y*kqv.y + v3.z*kqv.z + v3.w*kqv.w;
        s += __shfl_xor(s, 8); s += __shfl_xor(s, 4);
        s += __shfl_xor(s, 2); s += __shfl_xor(s, 1);
        if (sub == 0 && lr < RPB) { float sv = s * 0.125f;
            av[lr] = sv; __builtin_nontemporal_store(sv, attng + lr); }
    }
#undef ISSUE
#undef REDUCE
    __syncthreads();

    // local top-5 of av[0..511] (pads are -INF); ties -> lowest index
    float* pv = pval + (size_t)blockIdx.x * TOPK;
    int*   pi = pidx + (size_t)blockIdx.x * TOPK;
    for (int p = 0; p < TOPK; ++p) {
        float v0 = av[t], v1 = av[t + 256];
        float bv; int bi;
        if (v1 > v0) { bv = v1; bi = t + 256; } else { bv = v0; bi = t; }
#pragma unroll
        for (int m = 32; m >= 1; m >>= 1) {
            float ov = __shfl_xor(bv, m);
            int   oi = __shfl_xor(bi, m);
            if (ov > bv || (ov == bv && oi < bi)) { bv = ov; bi = oi; }
        }
        if ((t & 63) == 0) { redv[t >> 6] = bv; redi[t >> 6] = bi; }
        __syncthreads();
        if (t == 0) {
            for (int w = 1; w < 4; ++w)
                if (redv[w] > bv || (redv[w] == bv && redi[w] < bi)) { bv = redv[w]; bi = redi[w]; }
            pv[p] = bv; pi[p] = base + bi;   // global row idx within batch
            av[bi] = -INFINITY;
        }
        __syncthreads();
    }
}

// ---------------------------------------------------------------------------
// Kernel C: merge 50 candidates -> top-5 -> softmax -> gather -> MLP
// One block per batch, 256 threads (wave 0 does the selection).
// ---------------------------------------------------------------------------
__global__ __launch_bounds__(256) void merge_mlp_kernel(
    const float* __restrict__ pval,   // [B*50]
    const int*   __restrict__ pidx,   // [B*50]
    const float* __restrict__ raw,    // [B*5000*64]
    const float* __restrict__ Wp1, const float* __restrict__ bp1,
    const float* __restrict__ Wp2, const float* __restrict__ bp2,
    const float* __restrict__ Wp3, const float* __restrict__ bp3,
    float* __restrict__ out)
{
    __shared__ float topv[TOPK];
    __shared__ int   topi[TOPK];
    __shared__ float sc[TOPK];
    __shared__ __align__(16) float wsum[64];
    __shared__ __align__(16) float h1[64];
    __shared__ float h2[32];

    const int b = blockIdx.x, t = threadIdx.x;

    if (t < 64) {
        float v  = -INFINITY;
        int   idx = 0x7fffffff;
        if (t < CHUNKS * TOPK) { v = pval[b * 50 + t]; idx = pidx[b * 50 + t]; }
#pragma unroll
        for (int p = 0; p < TOPK; ++p) {
            float bv = v; int bi = idx;
#pragma unroll
            for (int m = 32; m >= 1; m >>= 1) {
                float ov = __shfl_xor(bv, m);
                int   oi = __shfl_xor(bi, m);
                if (ov > bv || (ov == bv && oi < bi)) { bv = ov; bi = oi; }
            }
            if (t == 0) { topv[p] = bv; topi[p] = bi; }
            if (idx == bi) v = -INFINITY;   // butterfly leaves winner in all lanes
        }
    }
    __syncthreads();

    if (t == 0) {
        float mx = topv[0];
        float e[TOPK], s = 0.f;
#pragma unroll
        for (int k = 0; k < TOPK; ++k) { e[k] = __expf(topv[k] - mx); s += e[k]; }
        float inv = 1.f / s;
#pragma unroll
        for (int k = 0; k < TOPK; ++k) {
            sc[k] = e[k] * inv;
            out[OFF_IDX + b * 10 + 2 * k]     = (float)(topi[k] / MAXLAG);
            out[OFF_IDX + b * 10 + 2 * k + 1] = (float)(topi[k] % MAXLAG);
            out[OFF_SCORE + b * TOPK + k]     = sc[k];
        }
    }
    __syncthreads();

    const float* rawb = raw + (size_t)b * NROWS * 64;
    if (t < 64) {
        float acc = 0.f;
#pragma unroll
        for (int k = 0; k < TOPK; ++k)
            acc += sc[k] * rawb[(size_t)topi[k] * 64 + t];
        wsum[t] = acc;
    }
    __syncthreads();
    if (t < 64) {
        float a = bp1[t];
        const float4* w = (const float4*)(Wp1 + t * 64);
        const float4* v = (const float4*)wsum;
#pragma unroll
        for (int k = 0; k < 16; ++k)
            a += w[k].x*v[k].x + w[k].y*v[k].y + w[k].z*v[k].z + w[k].w*v[k].w;
        h1[t] = fmaxf(a, 0.f);
    }
    __syncthreads();
    if (t < 32) {
        float a = bp2[t];
        const float4* w = (const float4*)(Wp2 + t * 64);
        const float4* v = (const float4*)h1;
#pragma unroll
        for (int k = 0; k < 16; ++k)
            a += w[k].x*v[k].x + w[k].y*v[k].y + w[k].z*v[k].z + w[k].w*v[k].w;
        h2[t] = fmaxf(a, 0.f);
    }
    __syncthreads();
    if (t == 0) {
        float a = bp3[0];
#pragma unroll
        for (int f = 0; f < 32; ++f) a += Wp3[f] * h2[f];
        out[b] = a;
    }
}

// ---------------------------------------------------------------------------
extern "C" void kernel_launch(void* const* d_in, const int* in_sizes, int n_in,
                              void* d_out, int out_size, void* d_ws, size_t ws_size,
                              hipStream_t stream) {
    const float* target = (const float*)d_in[0];
    const float* raw    = (const float*)d_in[1];
    const float* W_ih   = (const float*)d_in[2];
    const float* W_hh   = (const float*)d_in[3];
    const float* b_ih   = (const float*)d_in[4];
    const float* b_hh   = (const float*)d_in[5];
    const float* W_Q    = (const float*)d_in[6];
    const float* W_K    = (const float*)d_in[7];
    const float* Wp1    = (const float*)d_in[8];
    const float* bp1    = (const float*)d_in[9];
    const float* Wp2    = (const float*)d_in[10];
    const float* bp2    = (const float*)d_in[11];
    const float* Wp3    = (const float*)d_in[12];
    const float* bp3    = (const float*)d_in[13];

    float* out  = (float*)d_out;
    float* ws   = (float*)d_ws;
    float* kq   = ws;                       // [512*64]
    float* pval = ws + WS_PVAL;             // [512*10*5]
    int*   pidx = (int*)(ws + WS_PIDX);     // [512*10*5]
    float* attn_out = out + OFF_ATTN;

    hipLaunchKernelGGL(lstm_kq_kernel, dim3(B_SZ), dim3(256), 0, stream,
                       target, W_ih, W_hh, b_ih, b_hh, W_Q, W_K, kq);
    hipLaunchKernelGGL(attn_stream_topk_kernel, dim3(B_SZ * CHUNKS), dim3(256), 0, stream,
                       raw, kq, attn_out, pval, pidx);
    hipLaunchKernelGGL(merge_mlp_kernel, dim3(B_SZ), dim3(256), 0, stream,
                       pval, pidx, raw, Wp1, bp1, Wp2, bp2, Wp3, bp3, out);
}

// Round 8
// 189.043 us; speedup vs baseline: 1.1684x; 1.0222x over previous
//
#include <hip/hip_runtime.h>
#include <math.h>

// Problem constants
#define B_SZ   512
#define L_SEQ  30
#define F_DIM  64
#define N_LEAD 500
#define MAXLAG 10
#define H_DIM  64
#define NROWS  5000          // N_LEAD * MAXLAG
#define TOPK   5

// Output layout (flat float32):
// pred [512] | top_k_indices [512*5*2] | top_k_scores [512*5] | attn [512*5000]
#define OFF_IDX   512
#define OFF_SCORE 5632
#define OFF_ATTN  8192

typedef float v4f __attribute__((ext_vector_type(4)));

__device__ __forceinline__ float fast_sigmoid(float x) {
    return 1.f / (1.f + __expf(-x));
}
__device__ __forceinline__ float fast_tanh(float x) {
    float ax = fabsf(x);
    float t  = __expf(-2.f * ax);
    float r  = (1.f - t) / (1.f + t);
    return copysignf(r, x);
}

// 16 x float4 dot with 4 partial accumulators
__device__ __forceinline__ float dot16(const float4* __restrict__ w,
                                       const float4* __restrict__ v) {
    float a0 = 0.f, a1 = 0.f, a2 = 0.f, a3 = 0.f;
#pragma unroll
    for (int k = 0; k < 16; k += 4) {
        a0 += w[k+0].x*v[k+0].x + w[k+0].y*v[k+0].y + w[k+0].z*v[k+0].z + w[k+0].w*v[k+0].w;
        a1 += w[k+1].x*v[k+1].x + w[k+1].y*v[k+1].y + w[k+1].z*v[k+1].z + w[k+1].w*v[k+1].w;
        a2 += w[k+2].x*v[k+2].x + w[k+2].y*v[k+2].y + w[k+2].z*v[k+2].z + w[k+2].w*v[k+2].w;
        a3 += w[k+3].x*v[k+3].x + w[k+3].y*v[k+3].y + w[k+3].z*v[k+3].z + w[k+3].w*v[k+3].w;
    }
    return (a0 + a1) + (a2 + a3);
}

// ---------------------------------------------------------------------------
// Kernel A: LSTM (30 steps) + query = h@W_Q^T + kq = query@W_K  -> kq[B,64]
// (measured: LSTM + all launch overhead ~ 20.5us)
// ---------------------------------------------------------------------------
__global__ __launch_bounds__(256) void lstm_kq_kernel(
    const float* __restrict__ x,      // [B,30,64]
    const float* __restrict__ W_ih,   // [256,64]
    const float* __restrict__ W_hh,   // [256,64]
    const float* __restrict__ b_ih,   // [256]
    const float* __restrict__ b_hh,   // [256]
    const float* __restrict__ W_Q,    // [64,64]
    const float* __restrict__ W_K,    // [64,64]
    float* __restrict__ kq)           // [B,64]
{
    __shared__ __align__(16) float xs[L_SEQ * F_DIM];   // 7.5 KB
    __shared__ __align__(16) float hs[H_DIM];
    __shared__ __align__(16) float gates[256];

    const int b = blockIdx.x;
    const int t = threadIdx.x;

    for (int i = t; i < L_SEQ * F_DIM; i += 256)
        xs[i] = x[b * L_SEQ * F_DIM + i];
    if (t < H_DIM) hs[t] = 0.f;

    float4 wih[16], whh[16];
    const float4* wihp = (const float4*)(W_ih + t * 64);
    const float4* whhp = (const float4*)(W_hh + t * 64);
#pragma unroll
    for (int k = 0; k < 16; ++k) { wih[k] = wihp[k]; whh[k] = whhp[k]; }
    const float bsum = b_ih[t] + b_hh[t];

    float c = 0.f;
    __syncthreads();

    float gx = bsum + dot16(wih, (const float4*)xs);

    for (int step = 0; step < L_SEQ; ++step) {
        float g = gx + dot16(whh, (const float4*)hs);
        gates[t] = g;
        __syncthreads();
        if (t < H_DIM) {
            float ig = fast_sigmoid(gates[t]);
            float fg = fast_sigmoid(gates[t + 64]);
            float gg = fast_tanh(gates[t + 128]);
            float og = fast_sigmoid(gates[t + 192]);
            c = fg * c + ig * gg;
            hs[t] = og * fast_tanh(c);
        }
        if (step + 1 < L_SEQ)
            gx = bsum + dot16(wih, (const float4*)(xs + (step + 1) * F_DIM));
        __syncthreads();
    }

    if (t < H_DIM)
        gates[t] = dot16((const float4*)(W_Q + t * 64), (const float4*)hs);
    __syncthreads();
    if (t < F_DIM) {
        float a0 = 0.f, a1 = 0.f;
        for (int h = 0; h < H_DIM; h += 2) {
            a0 += gates[h]     * W_K[h * F_DIM + t];
            a1 += gates[h + 1] * W_K[(h + 1) * F_DIM + t];
        }
        kq[b * F_DIM + t] = a0 + a1;
    }
}

// ---------------------------------------------------------------------------
// Kernel B: attn streaming GEMV — wave-contiguous 16-lane-coop pattern +
// NON-TEMPORAL loads (best measured: ~4.15 TB/s). 5120 blocks x 256 threads.
// ---------------------------------------------------------------------------
#define CHUNKS 10
#define ROWS_PER_BLK 500
__global__ __launch_bounds__(256) void attn_kernel(
    const float* __restrict__ raw,    // [B*5000*64]
    const float* __restrict__ kq,     // [B,64]
    float* __restrict__ attn)         // [B*5000]
{
    const int b     = blockIdx.x / CHUNKS;
    const int chunk = blockIdx.x % CHUNKS;
    const int sub   = threadIdx.x & 15;   // 0..15 : position within row
    const int rg    = threadIdx.x >> 4;   // 0..15 : row group

    const float4 kqv = ((const float4*)(kq + b * 64))[sub];
    const int base   = chunk * ROWS_PER_BLK;
    const size_t rowb = (size_t)b * NROWS;

    for (int it = 0; it < 8; ++it) {
#pragma unroll
        for (int j = 0; j < 4; ++j) {
            int row = base + it * 64 + j * 16 + rg;
            if (row < base + ROWS_PER_BLK) {
                const v4f* pp = (const v4f*)(raw + ((rowb + row) << 6)) + sub;
                v4f v = __builtin_nontemporal_load(pp);
                float s = v.x * kqv.x + v.y * kqv.y + v.z * kqv.z + v.w * kqv.w;
                s += __shfl_xor(s, 8);
                s += __shfl_xor(s, 4);
                s += __shfl_xor(s, 2);
                s += __shfl_xor(s, 1);
                if (sub == 0) attn[rowb + row] = s * 0.125f;
            }
        }
    }
}

// ---------------------------------------------------------------------------
// Kernel C: per-batch top-5 (lax.top_k tie semantics) + softmax + gather + MLP
// ---------------------------------------------------------------------------
__global__ __launch_bounds__(256) void topk_mlp_kernel(
    const float* __restrict__ attn,   // [B*5000]
    const float* __restrict__ raw,    // [B*5000*64]
    const float* __restrict__ Wp1, const float* __restrict__ bp1,
    const float* __restrict__ Wp2, const float* __restrict__ bp2,
    const float* __restrict__ Wp3, const float* __restrict__ bp3,
    float* __restrict__ out)
{
    __shared__ __align__(16) float av[NROWS];       // 20 KB
    __shared__ float redv[4];
    __shared__ int   redi[4];
    __shared__ float topv[TOPK];
    __shared__ int   topi[TOPK];
    __shared__ float sc[TOPK];
    __shared__ __align__(16) float wsum[64];
    __shared__ __align__(16) float h1[64];
    __shared__ float h2[32];

    const int b = blockIdx.x, t = threadIdx.x;

    const float4* ain = (const float4*)(attn + (size_t)b * NROWS);
    float4* av4 = (float4*)av;
    for (int i = t; i < NROWS / 4; i += 256) av4[i] = ain[i];
    __syncthreads();

    for (int pp = 0; pp < TOPK; ++pp) {
        float bv = -INFINITY; int bi = 0x7fffffff;
        for (int i = t; i < NROWS; i += 256) {
            float v = av[i];
            if (v > bv || (v == bv && i < bi)) { bv = v; bi = i; }
        }
#pragma unroll
        for (int m = 32; m >= 1; m >>= 1) {
            float ov = __shfl_xor(bv, m);
            int   oi = __shfl_xor(bi, m);
            if (ov > bv || (ov == bv && oi < bi)) { bv = ov; bi = oi; }
        }
        if ((t & 63) == 0) { redv[t >> 6] = bv; redi[t >> 6] = bi; }
        __syncthreads();
        if (t == 0) {
            for (int w = 1; w < 4; ++w)
                if (redv[w] > bv || (redv[w] == bv && redi[w] < bi)) { bv = redv[w]; bi = redi[w]; }
            topv[pp] = bv; topi[pp] = bi;
            av[bi] = -INFINITY;
        }
        __syncthreads();
    }

    if (t == 0) {
        float mx = topv[0];
        float e[TOPK], s = 0.f;
#pragma unroll
        for (int k = 0; k < TOPK; ++k) { e[k] = __expf(topv[k] - mx); s += e[k]; }
        float inv = 1.f / s;
#pragma unroll
        for (int k = 0; k < TOPK; ++k) {
            sc[k] = e[k] * inv;
            out[OFF_IDX + b * 10 + 2 * k]     = (float)(topi[k] / MAXLAG);
            out[OFF_IDX + b * 10 + 2 * k + 1] = (float)(topi[k] % MAXLAG);
            out[OFF_SCORE + b * TOPK + k]     = sc[k];
        }
    }
    __syncthreads();

    if (t < 64) {
        float acc = 0.f;
#pragma unroll
        for (int k = 0; k < TOPK; ++k)
            acc += sc[k] * raw[((size_t)b * NROWS + topi[k]) * 64 + t];
        wsum[t] = acc;
    }
    __syncthreads();
    if (t < 64) {
        float a = bp1[t];
        const float4* w = (const float4*)(Wp1 + t * 64);
        const float4* v = (const float4*)wsum;
#pragma unroll
        for (int k = 0; k < 16; ++k)
            a += w[k].x*v[k].x + w[k].y*v[k].y + w[k].z*v[k].z + w[k].w*v[k].w;
        h1[t] = fmaxf(a, 0.f);
    }
    __syncthreads();
    if (t < 32) {
        float a = bp2[t];
        const float4* w = (const float4*)(Wp2 + t * 64);
        const float4* v = (const float4*)h1;
#pragma unroll
        for (int k = 0; k < 16; ++k)
            a += w[k].x*v[k].x + w[k].y*v[k].y + w[k].z*v[k].z + w[k].w*v[k].w;
        h2[t] = fmaxf(a, 0.f);
    }
    __syncthreads();
    if (t == 0) {
        float a = bp3[0];
#pragma unroll
        for (int f = 0; f < 32; ++f) a += Wp3[f] * h2[f];
        out[b] = a;
    }
}

// ---------------------------------------------------------------------------
extern "C" void kernel_launch(void* const* d_in, const int* in_sizes, int n_in,
                              void* d_out, int out_size, void* d_ws, size_t ws_size,
                              hipStream_t stream) {
    const float* target = (const float*)d_in[0];
    const float* raw    = (const float*)d_in[1];
    const float* W_ih   = (const float*)d_in[2];
    const float* W_hh   = (const float*)d_in[3];
    const float* b_ih   = (const float*)d_in[4];
    const float* b_hh   = (const float*)d_in[5];
    const float* W_Q    = (const float*)d_in[6];
    const float* W_K    = (const float*)d_in[7];
    const float* Wp1    = (const float*)d_in[8];
    const float* bp1    = (const float*)d_in[9];
    const float* Wp2    = (const float*)d_in[10];
    const float* bp2    = (const float*)d_in[11];
    const float* Wp3    = (const float*)d_in[12];
    const float* bp3    = (const float*)d_in[13];

    float* out      = (float*)d_out;
    float* kq       = (float*)d_ws;                 // [512*64] floats
    float* attn_out = out + OFF_ATTN;

    hipLaunchKernelGGL(lstm_kq_kernel, dim3(B_SZ), dim3(256), 0, stream,
                       target, W_ih, W_hh, b_ih, b_hh, W_Q, W_K, kq);
    hipLaunchKernelGGL(attn_kernel, dim3(B_SZ * CHUNKS), dim3(256), 0, stream,
                       raw, kq, attn_out);
    hipLaunchKernelGGL(topk_mlp_kernel, dim3(B_SZ), dim3(256), 0, stream,
                       attn_out, raw, Wp1, bp1, Wp2, bp2, Wp3, bp3, out);
}